// Round 6
// baseline (120.237 us; speedup 1.0000x reference)
//
#include <hip/hip_runtime.h>

// AtomEncoderLayer fused single-kernel, round 6: wave-owned dot products.
// B=4, N=32, D=128, H=8, NC=27, DK=16, DFF=512, L=864.
// One block per (b,i), 1024 threads (16 waves), 10 barriers / 11 phases.
// All partial+combine pairs (q, att, y/Wo, FFN1, FFN2) replaced by
// wave-owned dots: wave w owns output cols, lane owns stride-G e-subset,
// weights prefetched as register COLUMNS, shfl_xor reduce. qAxk/qGk/S3
// computed inside the softmax wave (register-resident, no LDS arrays).
// FFN2 reduce-lane stores out directly. pf_s partial buffer eliminated.
// Algebra identical to R2/R3/R5 verified versions.

#define B_ 4
#define N_ 32
#define D_ 128
#define H_ 8
#define NC_ 27
#define DFF_ 512
#define L_ (NC_*N_)        // 864

__device__ __forceinline__ float wred(float v){
  #pragma unroll
  for (int off = 32; off; off >>= 1) v += __shfl_xor(v, off);
  return v;
}

__global__ __launch_bounds__(1024) void k_fused(
    const float* __restrict__ x, const int* __restrict__ mask,
    const float* __restrict__ coords,
    const float* __restrict__ Wp, const float* __restrict__ bp,
    const float* __restrict__ Wq, const float* __restrict__ bq,
    const float* __restrict__ Wk, const float* __restrict__ bk,
    const float* __restrict__ Wv, const float* __restrict__ bv,
    const float* __restrict__ Wo, const float* __restrict__ bo,
    const float* __restrict__ g1, const float* __restrict__ b1,
    const float* __restrict__ g2, const float* __restrict__ b2,
    const float* __restrict__ W1, const float* __restrict__ bf1,
    const float* __restrict__ W2, const float* __restrict__ bfb2,
    float* __restrict__ out)
{
  __shared__ float is_s[L_];           // inv_std per key
  __shared__ float dc_s[3][L_];        // rel-coords cache
  __shared__ float xg_s[N_][D_+1];     // centered x * g1; +1 pad -> bank (n+e)%32
  __shared__ float zz_s[H_][D_+1];     // u_h then ZZ_h; +1 pad
  __shared__ float w_s[3][D_];         // raw Wp rows
  __shared__ float wcg_s[3][D_];       // centered Wp * g1
  __shared__ float g1_s[D_], b1_s[D_], bp_s[D_], bq_s[D_], bk_s[D_];
  __shared__ float g2_s[D_], b2_s[D_], bv_s[D_], bo_s[D_], bfb2_s[D_];
  __shared__ float bf1_s[DFF_];
  __shared__ float q_s[D_], hn_s[D_], hn2_s[D_], att_s[D_], y_s[D_], xi_s[D_];
  __shared__ float varx_s[N_];
  __shared__ float dxp_s[N_][3];
  __shared__ int   mask_s[N_];
  __shared__ float cq_s[NC_][3];
  __shared__ float mwp_s[3], P6_s[6];
  __shared__ float pmax_s[H_][2];
  __shared__ float Tnp_s[H_][2][N_];
  __shared__ float Sp_s[H_][2], RDp_s[H_][2][3];
  __shared__ float f_s[DFF_];

  int bi = blockIdx.x;                 // b*32+i
  int b = bi >> 5, i = bi & 31;
  int tid = threadIdx.x, wave = tid >> 6, lane = tid & 63;
  int eg = lane >> 3, dl = lane & 7;   // 8-col ownership mapping
  int dq = 8*wave + dl;                // owned output col (q/att/y/ffn2)
  int e0 = 2*lane, e1 = 2*lane+1;      // float2 e-pair mapping

  // ================= Ph0: stage + prefetch Wq cols + Wk tiles =========
  int r0 = wave*2, r1 = wave*2+1;
  float2 xA = *(const float2*)&x[(size_t)(b*N_+r0)*D_ + e0];
  float2 xB = *(const float2*)&x[(size_t)(b*N_+r1)*D_ + e0];
  float ck0=0.f, ck1=0.f, ck2=0.f;
  if (tid < L_){
    int c = tid >> 5, n = tid & 31;
    const float* ck = coords + ((size_t)(b*NC_+c)*N_ + n)*3;
    ck0 = ck[0]; ck1 = ck[1]; ck2 = ck[2];
  }
  float wqr[16];                       // Wq column dq, rows 8k+eg
  #pragma unroll
  for (int k=0;k<16;k++) wqr[k] = Wq[(size_t)(8*k+eg)*D_ + dq];
  float4 wk4[4];                       // for u phase: (h=tid>>7, e=tid&127)
  {
    int h = tid>>7, e = tid&127;
    #pragma unroll
    for (int k=0;k<4;k++)
      wk4[k] = *(const float4*)(Wk + (size_t)e*D_ + h*16 + k*4);
  }
  if (tid < 384) w_s[tid>>7][tid&127] = Wp[tid];
  if      (tid < 128)  g1_s[tid]      = g1[tid];
  else if (tid < 256)  b1_s[tid-128]  = b1[tid-128];
  else if (tid < 384)  bp_s[tid-256]  = bp[tid-256];
  else if (tid < 512)  bq_s[tid-384]  = bq[tid-384];
  else if (tid < 640)  bk_s[tid-512]  = bk[tid-512];
  else if (tid < 768)  g2_s[tid-640]  = g2[tid-640];
  else if (tid < 896)  b2_s[tid-768]  = b2[tid-768];
  else                 bv_s[tid-896]  = bv[tid-896];
  if      (tid < 128)  bo_s[tid]      = bo[tid];
  else if (tid < 256)  bfb2_s[tid-128]= bfb2[tid-128];
  else if (tid < 768)  bf1_s[tid-256] = bf1[tid-256];
  else if (tid < 800)  mask_s[tid-768]= mask[b*N_ + (tid-768)];
  else if (tid < 881){
    int t = tid-800;
    cq_s[t/3][t%3] = coords[((size_t)(b*NC_ + t/3)*N_ + i)*3 + t%3];
  }
  __syncthreads();   // B1

  // == Ph1: rows (xg,varx,dxp) + hn_i/xi_i by owner; dc; mwp; P6 =======
  {
    float t0 = xA.x + bp_s[e0], t1 = xA.y + bp_s[e1];
    float mean = wred(t0+t1)*(1.f/D_);
    float h0 = t0-mean, h1 = t1-mean;
    xg_s[r0][e0] = h0*g1_s[e0];
    xg_s[r0][e1] = h1*g1_s[e1];
    float vv = h0*h0 + h1*h1;
    float d0 = h0*w_s[0][e0] + h1*w_s[0][e1];
    float d1 = h0*w_s[1][e0] + h1*w_s[1][e1];
    float d2 = h0*w_s[2][e0] + h1*w_s[2][e1];
    #pragma unroll
    for (int off=32; off; off>>=1){
      vv += __shfl_xor(vv,off); d0 += __shfl_xor(d0,off);
      d1 += __shfl_xor(d1,off); d2 += __shfl_xor(d2,off);
    }
    if (lane==0){ varx_s[r0]=vv*(1.f/D_);
      dxp_s[r0][0]=d0; dxp_s[r0][1]=d1; dxp_s[r0][2]=d2; }
    if (r0 == i){
      float isq = rsqrtf(vv*(1.f/D_)+1e-5f);
      hn_s[e0] = h0*isq*g1_s[e0] + b1_s[e0];
      hn_s[e1] = h1*isq*g1_s[e1] + b1_s[e1];
      xi_s[e0] = t0; xi_s[e1] = t1;
    }
    t0 = xB.x + bp_s[e0]; t1 = xB.y + bp_s[e1];
    mean = wred(t0+t1)*(1.f/D_);
    h0 = t0-mean; h1 = t1-mean;
    xg_s[r1][e0] = h0*g1_s[e0];
    xg_s[r1][e1] = h1*g1_s[e1];
    vv = h0*h0 + h1*h1;
    d0 = h0*w_s[0][e0] + h1*w_s[0][e1];
    d1 = h0*w_s[1][e0] + h1*w_s[1][e1];
    d2 = h0*w_s[2][e0] + h1*w_s[2][e1];
    #pragma unroll
    for (int off=32; off; off>>=1){
      vv += __shfl_xor(vv,off); d0 += __shfl_xor(d0,off);
      d1 += __shfl_xor(d1,off); d2 += __shfl_xor(d2,off);
    }
    if (lane==0){ varx_s[r1]=vv*(1.f/D_);
      dxp_s[r1][0]=d0; dxp_s[r1][1]=d1; dxp_s[r1][2]=d2; }
    if (r1 == i){
      float isq = rsqrtf(vv*(1.f/D_)+1e-5f);
      hn_s[e0] = h0*isq*g1_s[e0] + b1_s[e0];
      hn_s[e1] = h1*isq*g1_s[e1] + b1_s[e1];
      xi_s[e0] = t0; xi_s[e1] = t1;
    }
  }
  float dc0=0.f, dc1=0.f, dc2=0.f;
  if (tid < L_){
    int c = tid >> 5;
    dc0 = ck0 - cq_s[c][0]; dc1 = ck1 - cq_s[c][1]; dc2 = ck2 - cq_s[c][2];
    dc_s[0][tid]=dc0; dc_s[1][tid]=dc1; dc_s[2][tid]=dc2;
  }
  if (wave >= 8 && wave < 11){
    int j = wave - 8;
    float s = w_s[j][lane] + w_s[j][lane+64];
    s = wred(s);
    if (lane==0) mwp_s[j] = s*(1.f/D_);
  }
  if (wave >= 10){
    int idx = wave - 10;
    int ja = (idx>=3) + (idx>=5);
    int jb = idx - (idx>=3)*2 - (idx>=5);
    float s = w_s[ja][lane]*w_s[jb][lane] + w_s[ja][lane+64]*w_s[jb][lane+64];
    s = wred(s);
    if (lane==0) P6_s[idx] = s;
  }
  __syncthreads();   // B2

  // ===== Ph2: q wave-owned + is_s (tid<864, reg dc) + wcg =====
  {
    float acc = 0.f;
    #pragma unroll
    for (int k=0;k<16;k++) acc += wqr[k]*hn_s[8*k+eg];
    acc += __shfl_xor(acc,8); acc += __shfl_xor(acc,16); acc += __shfl_xor(acc,32);
    if (eg==0) q_s[dq] = acc + bq_s[dq];
  }
  if (tid < L_){
    int n = tid & 31;
    float m0 = mwp_s[0], m1 = mwp_s[1], m2 = mwp_s[2];
    float M00 = P6_s[0]-D_*m0*m0, M01 = P6_s[1]-D_*m0*m1;
    float M02 = P6_s[2]-D_*m0*m2, M11 = P6_s[3]-D_*m1*m1;
    float M12 = P6_s[4]-D_*m1*m2, M22 = P6_s[5]-D_*m2*m2;
    float quad = dc0*dc0*M00 + dc1*dc1*M11 + dc2*dc2*M22
               + 2.f*(dc0*dc1*M01 + dc0*dc2*M02 + dc1*dc2*M12);
    float lin  = dc0*dxp_s[n][0] + dc1*dxp_s[n][1] + dc2*dxp_s[n][2];
    float E = varx_s[n] + (quad + 2.f*lin)*(1.f/D_);
    is_s[tid] = rsqrtf(fmaxf(E, 0.f) + 1e-5f);
  }
  if (tid < 384){ int j=tid>>7, e=tid&127;
    wcg_s[j][e] = (w_s[j][e] - mwp_s[j])*g1_s[e]; }
  __syncthreads();   // B3

  // ===== Ph3: u_h[e] (wk4) -> zz_s; prefetch Wv cols =====
  float wvr[16];
  #pragma unroll
  for (int k=0;k<16;k++) wvr[k] = Wv[(size_t)(8*k+eg)*D_ + dq];
  {
    int h = tid>>7, e = tid&127;
    float s = 0.f;
    #pragma unroll
    for (int kq=0; kq<4; kq++){
      s += wk4[kq].x*q_s[h*16+kq*4+0] + wk4[kq].y*q_s[h*16+kq*4+1]
         + wk4[kq].z*q_s[h*16+kq*4+2] + wk4[kq].w*q_s[h*16+kq*4+3];
    }
    zz_s[h][e] = s;                    // raw u
  }
  __syncthreads();   // B4

  // ===== Ph4: in-wave qAxk + qGk/S3 + scores + softmax partials =====
  int h4 = wave>>1, sub = wave&1, n2 = lane&31, half2 = lane>>5;
  int q4c = sub*2 + half2, c0 = q4c*7, c1 = (q4c==3) ? NC_ : c0+7;
  {
    // qAxk[h4][n2]: e-parity split by half2, pair-combine via xor 32
    float qa = 0.f;
    #pragma unroll
    for (int k=0;k<64;k++) qa += xg_s[n2][2*k+half2]*zz_s[h4][2*k+half2];
    qa += __shfl_xor(qa, 32);
    // qGk/S3 in-register (redundant across the wave pair, wave-uniform)
    float u0 = zz_s[h4][lane], u1 = zz_s[h4][lane+64];
    float s3 = b1_s[lane]*u0 + b1_s[lane+64]*u1;
    if (lane < 16) s3 += q_s[h4*16+lane]*bk_s[h4*16+lane];
    float qg0 = wcg_s[0][lane]*u0 + wcg_s[0][lane+64]*u1;
    float qg1 = wcg_s[1][lane]*u0 + wcg_s[1][lane+64]*u1;
    float qg2 = wcg_s[2][lane]*u0 + wcg_s[2][lane+64]*u1;
    #pragma unroll
    for (int off=32; off; off>>=1){
      s3  += __shfl_xor(s3,off);  qg0 += __shfl_xor(qg0,off);
      qg1 += __shfl_xor(qg1,off); qg2 += __shfl_xor(qg2,off);
    }
    // scores (quarter c-range) + wave max + exp + partials
    bool mk = mask_s[n2] != 0;
    float sc[7];
    float M = -3.0e38f;
    #pragma unroll
    for (int t=0; t<7; t++){
      int c = c0+t;
      if (c < c1){
        int l = c*N_ + n2;
        float v = 0.25f*(is_s[l]*(qa + dc_s[0][l]*qg0 + dc_s[1][l]*qg1
                                     + dc_s[2][l]*qg2) + s3);
        sc[t] = mk ? v : -1e9f;
      } else sc[t] = -3.0e38f;
      M = fmaxf(M, sc[t]);
    }
    #pragma unroll
    for (int off=32; off; off>>=1) M = fmaxf(M, __shfl_xor(M, off));
    if (lane==0) pmax_s[h4][sub] = M;
    float S=0.f, Tn=0.f, rr0=0.f, rr1=0.f, rr2=0.f;
    #pragma unroll
    for (int t=0; t<7; t++){
      int c = c0+t;
      if (c < c1){
        int l = c*N_ + n2;
        float w_ = __expf(sc[t] - M);
        float tt = w_ * is_s[l];
        S += w_; Tn += tt;
        rr0 += tt*dc_s[0][l]; rr1 += tt*dc_s[1][l]; rr2 += tt*dc_s[2][l];
      }
    }
    float Tn2 = Tn + __shfl_xor(Tn, 32);
    if (lane < 32) Tnp_s[h4][sub][lane] = Tn2;
    #pragma unroll
    for (int off=32; off; off>>=1){
      S   += __shfl_xor(S,off);   rr0 += __shfl_xor(rr0,off);
      rr1 += __shfl_xor(rr1,off); rr2 += __shfl_xor(rr2,off);
    }
    if (lane==0){ Sp_s[h4][sub]=S;
      RDp_s[h4][sub][0]=rr0; RDp_s[h4][sub][1]=rr1; RDp_s[h4][sub][2]=rr2; }
  }
  __syncthreads();   // B5

  // ===== Ph5: ZZ_h[e] with sub-wave rescale; prefetch Wo cols =====
  float wor[16];
  #pragma unroll
  for (int k=0;k<16;k++) wor[k] = Wo[(size_t)(8*k+eg)*D_ + dq];
  {
    int h = tid>>7, e = tid&127;
    float M0 = pmax_s[h][0], M1 = pmax_s[h][1];
    float Mx = fmaxf(M0, M1);
    float f0 = __expf(M0-Mx), f1 = __expf(M1-Mx);
    float S = Sp_s[h][0]*f0 + Sp_s[h][1]*f1;
    float rS = 1.f / fmaxf(S, 1e-30f);
    float z = 0.f;
    #pragma unroll 8
    for (int n=0; n<N_; n++){
      float Tn = Tnp_s[h][0][n]*f0 + Tnp_s[h][1][n]*f1;
      z += Tn * xg_s[n][e];
    }
    float R0 = RDp_s[h][0][0]*f0 + RDp_s[h][1][0]*f1;
    float R1 = RDp_s[h][0][1]*f0 + RDp_s[h][1][1]*f1;
    float R2 = RDp_s[h][0][2]*f0 + RDp_s[h][1][2]*f1;
    z += R0*wcg_s[0][e] + R1*wcg_s[1][e] + R2*wcg_s[2][e];
    zz_s[h][e] = z*rS + b1_s[e];       // u dead (consumed in Ph4)
  }
  __syncthreads();   // B6

  // ===== Ph6: att wave-owned (wvr) =====
  {
    int ha = wave>>1;                  // = dq>>4 for all 8 owned cols
    float acc = 0.f;
    #pragma unroll
    for (int k=0;k<16;k++) acc += wvr[k]*zz_s[ha][8*k+eg];
    acc += __shfl_xor(acc,8); acc += __shfl_xor(acc,16); acc += __shfl_xor(acc,32);
    if (eg==0) att_s[dq] = acc + bv_s[dq];
  }
  __syncthreads();   // B7

  // ===== Ph7: y wave-owned (wor) =====
  {
    float acc = 0.f;
    #pragma unroll
    for (int k=0;k<16;k++) acc += wor[k]*att_s[8*k+eg];
    acc += __shfl_xor(acc,8); acc += __shfl_xor(acc,16); acc += __shfl_xor(acc,32);
    if (eg==0) y_s[dq] = xi_s[dq] + bo_s[dq] + acc;
  }
  __syncthreads();   // B8

  // ===== Ph8: prefetch W1 cols (all waves); LN2 (wave 0) =====
  int cl = lane & 31, eh = lane >> 5, col = 32*wave + cl;
  float w1r[64];
  #pragma unroll
  for (int k=0;k<64;k++) w1r[k] = W1[(size_t)(2*k+eh)*DFF_ + col];
  if (wave == 0){
    float y0 = y_s[e0], y1 = y_s[e1];
    float mean = wred(y0+y1)*(1.f/D_);
    float v0 = y0-mean, v1 = y1-mean;
    float var = wred(v0*v0+v1*v1)*(1.f/D_);
    float isd = rsqrtf(var + 1e-5f);
    hn2_s[e0] = v0*isd*g2_s[e0] + b2_s[e0];
    hn2_s[e1] = v1*isd*g2_s[e1] + b2_s[e1];
  }
  __syncthreads();   // B9

  // ===== Ph9: FFN1 wave-owned (w1r); then prefetch W2 cols =====
  int jg = lane >> 3;
  float w2r[64];
  {
    float acc = 0.f;
    #pragma unroll
    for (int k=0;k<64;k++) acc += w1r[k]*hn2_s[2*k+eh];
    acc += __shfl_xor(acc, 32);
    if (eh==0) f_s[col] = fmaxf(acc + bf1_s[col], 0.f);
  }
  #pragma unroll
  for (int k=0;k<64;k++) w2r[k] = W2[(size_t)(8*k+jg)*D_ + dq];
  __syncthreads();   // B10

  // ===== Ph10: FFN2 wave-owned (w2r) + out store =====
  {
    float acc = 0.f;
    #pragma unroll
    for (int k=0;k<64;k++) acc += w2r[k]*f_s[8*k+jg];
    acc += __shfl_xor(acc,8); acc += __shfl_xor(acc,16); acc += __shfl_xor(acc,32);
    if (jg==0) out[(size_t)bi*D_ + dq] = y_s[dq] + bfb2_s[dq] + acc;
  }
}

extern "C" void kernel_launch(void* const* d_in, const int* in_sizes, int n_in,
                              void* d_out, int out_size, void* d_ws, size_t ws_size,
                              hipStream_t stream){
  const float* x      = (const float*)d_in[0];
  const int*   mask   = (const int*)  d_in[1];
  const float* coords = (const float*)d_in[2];
  const float* Wp     = (const float*)d_in[3];
  const float* bp     = (const float*)d_in[4];
  const float* Wq     = (const float*)d_in[5];
  const float* bq     = (const float*)d_in[6];
  const float* Wk     = (const float*)d_in[7];
  const float* bk     = (const float*)d_in[8];
  const float* Wv     = (const float*)d_in[9];
  const float* bv     = (const float*)d_in[10];
  const float* Wo     = (const float*)d_in[11];
  const float* bo     = (const float*)d_in[12];
  const float* g1     = (const float*)d_in[13];
  const float* b1     = (const float*)d_in[14];
  const float* g2     = (const float*)d_in[15];
  const float* b2     = (const float*)d_in[16];
  const float* W1     = (const float*)d_in[17];
  const float* bf1    = (const float*)d_in[18];
  const float* W2     = (const float*)d_in[19];
  const float* bfb2   = (const float*)d_in[20];

  k_fused<<<B_*N_, 1024, 0, stream>>>(x, mask, coords, Wp, bp, Wq, bq, Wk, bk,
                                      Wv, bv, Wo, bo, g1, b1, g2, b2,
                                      W1, bf1, W2, bfb2, (float*)d_out);
}

// Round 7
// 116.685 us; speedup vs baseline: 1.0304x; 1.0304x over previous
//
#include <hip/hip_runtime.h>

// AtomEncoderLayer fused single-kernel, round 7: R3 base + drain consolidation
// + shfl-fused combines. B=4, N=32, D=128, H=8, NC=27, DFF=512, L=864.
// One block per (b,i), 1024 threads (16 waves), 15 barriers.
// vs R3 (best, 112.65):
//  - Wv/Wo prefetch moved to P0: all 4 small-weight HBM drains merge into B1.
//  - q-combine fused into u-phase: lanes 0-15 of each head-wave combine the
//    32 LDS partials, __shfl broadcasts q into the wk4 dot. -1 phase/barrier.
//  - att-combine fused into Wo-phase likewise (lanes 0-7 + __shfl), writing
//    to a second buffer pf2 (no read/write race). -1 phase/barrier.
//  - owner-wave hn_i in P1 and merged softmax (own-wave max, rescale in ZZ),
//    both verified in R5/R6 runs. -1 barrier.
// All weight loads stay float4-coalesced (R6's scalar-gather mistake avoided).
// Algebra identical to verified R2/R3 lineage; combine orders bit-identical.

#define B_ 4
#define N_ 32
#define D_ 128
#define H_ 8
#define NC_ 27
#define DFF_ 512
#define L_ (NC_*N_)        // 864

__device__ __forceinline__ float wred(float v){
  #pragma unroll
  for (int off = 32; off; off >>= 1) v += __shfl_xor(v, off);
  return v;
}

__global__ __launch_bounds__(1024) void k_fused(
    const float* __restrict__ x, const int* __restrict__ mask,
    const float* __restrict__ coords,
    const float* __restrict__ Wp, const float* __restrict__ bp,
    const float* __restrict__ Wq, const float* __restrict__ bq,
    const float* __restrict__ Wk, const float* __restrict__ bk,
    const float* __restrict__ Wv, const float* __restrict__ bv,
    const float* __restrict__ Wo, const float* __restrict__ bo,
    const float* __restrict__ g1, const float* __restrict__ b1,
    const float* __restrict__ g2, const float* __restrict__ b2,
    const float* __restrict__ W1, const float* __restrict__ bf1,
    const float* __restrict__ W2, const float* __restrict__ bfb2,
    float* __restrict__ out)
{
  __shared__ float is_s[L_];           // inv_std per key
  __shared__ float dc_s[3][L_];        // rel-coords cache
  __shared__ float xg_s[N_][D_+1];     // centered x * g1; +1 pad
  __shared__ float zz_s[H_][D_+1];     // u_h then ZZ_h; +1 pad
  __shared__ float w_s[3][D_];         // raw Wp rows
  __shared__ float wcg_s[3][D_];       // centered Wp * g1
  __shared__ float g1_s[D_], b1_s[D_], bp_s[D_], bq_s[D_], bk_s[D_];
  __shared__ float g2_s[D_], b2_s[D_], bv_s[D_], bo_s[D_], bfb2_s[D_];
  __shared__ float bf1_s[DFF_];
  __shared__ float q_s[D_], hn_s[D_], hn2_s[D_], y_s[D_];
  __shared__ float qAxk_s[H_][N_];
  __shared__ float qGk_s[H_][3];
  __shared__ float S3_s[H_];
  __shared__ float varx_s[N_];
  __shared__ float dxp_s[N_][3];
  __shared__ int   mask_s[N_];
  __shared__ float cq_s[NC_][3];
  __shared__ float mwp_s[3], P6_s[6];
  __shared__ float pmax_s[H_][2];
  __shared__ float Tnp_s[H_][2][N_];
  __shared__ float Sp_s[H_][2], RDp_s[H_][2][3];
  __shared__ float f_s[DFF_];
  __shared__ float pf_s[4096];         // partial buffer A
  __shared__ float pf2_s[4096];        // partial buffer B (fused-phase safety)
  float4* pf4  = (float4*)pf_s;
  float4* pf24 = (float4*)pf2_s;

  int bi = blockIdx.x;                 // b*32+i
  int b = bi >> 5, i = bi & 31;
  int tid = threadIdx.x, wave = tid >> 6, lane = tid & 63;
  int es = tid >> 5, d4 = tid & 31;    // 32 e-slots x 32 d4 mapping
  int e0 = 2*lane, e1 = 2*lane+1;      // float2 e-pair mapping

  // ========== P0: stage + prefetch Wq/Wk/Wv/Wo (one drain at B1) =======
  int r0 = wave*2, r1 = wave*2+1;
  float2 xA = *(const float2*)&x[(size_t)(b*N_+r0)*D_ + e0];
  float2 xB = *(const float2*)&x[(size_t)(b*N_+r1)*D_ + e0];
  float2 xI = {0.f, 0.f};
  if (wave == 0) xI = *(const float2*)&x[(size_t)bi*D_ + e0];
  float ck0=0.f, ck1=0.f, ck2=0.f;
  if (tid < L_){
    int c = tid >> 5, n = tid & 31;
    const float* ck = coords + ((size_t)(b*NC_+c)*N_ + n)*3;
    ck0 = ck[0]; ck1 = ck[1]; ck2 = ck[2];
  }
  float4 wq4[4], wv4[4], wo4[4];
  #pragma unroll
  for (int k=0;k<4;k++){
    wq4[k] = *(const float4*)(Wq + (size_t)(es*4+k)*D_ + d4*4);
    wv4[k] = *(const float4*)(Wv + (size_t)(es*4+k)*D_ + d4*4);
    wo4[k] = *(const float4*)(Wo + (size_t)(es*4+k)*D_ + d4*4);
  }
  float4 wk4[4];
  {
    int h = tid>>7, e = tid&127;
    #pragma unroll
    for (int k=0;k<4;k++)
      wk4[k] = *(const float4*)(Wk + (size_t)e*D_ + h*16 + k*4);
  }
  if (tid < 384) w_s[tid>>7][tid&127] = Wp[tid];
  if      (tid < 128)  g1_s[tid]      = g1[tid];
  else if (tid < 256)  b1_s[tid-128]  = b1[tid-128];
  else if (tid < 384)  bp_s[tid-256]  = bp[tid-256];
  else if (tid < 512)  bq_s[tid-384]  = bq[tid-384];
  else if (tid < 640)  bk_s[tid-512]  = bk[tid-512];
  else if (tid < 768)  g2_s[tid-640]  = g2[tid-640];
  else if (tid < 896)  b2_s[tid-768]  = b2[tid-768];
  else                 bv_s[tid-896]  = bv[tid-896];
  if      (tid < 128)  bo_s[tid]      = bo[tid];
  else if (tid < 256)  bfb2_s[tid-128]= bfb2[tid-128];
  else if (tid < 768)  bf1_s[tid-256] = bf1[tid-256];
  else if (tid < 800)  mask_s[tid-768]= mask[b*N_ + (tid-768)];
  else if (tid < 881){
    int t = tid-800;
    cq_s[t/3][t%3] = coords[((size_t)(b*NC_ + t/3)*N_ + i)*3 + t%3];
  }
  __syncthreads();   // B1

  // == P1: rows (xg,varx,dxp) + owner-wave hn_i; dc; mwp; P6 ===========
  {
    float t0 = xA.x + bp_s[e0], t1 = xA.y + bp_s[e1];
    float mean = wred(t0+t1)*(1.f/D_);
    float h0 = t0-mean, h1 = t1-mean;
    xg_s[r0][e0] = h0*g1_s[e0];
    xg_s[r0][e1] = h1*g1_s[e1];
    float vv = h0*h0 + h1*h1;
    float d0 = h0*w_s[0][e0] + h1*w_s[0][e1];
    float d1 = h0*w_s[1][e0] + h1*w_s[1][e1];
    float d2 = h0*w_s[2][e0] + h1*w_s[2][e1];
    #pragma unroll
    for (int off=32; off; off>>=1){
      vv += __shfl_xor(vv,off); d0 += __shfl_xor(d0,off);
      d1 += __shfl_xor(d1,off); d2 += __shfl_xor(d2,off);
    }
    if (lane==0){ varx_s[r0]=vv*(1.f/D_);
      dxp_s[r0][0]=d0; dxp_s[r0][1]=d1; dxp_s[r0][2]=d2; }
    if (r0 == i){
      float isq = rsqrtf(vv*(1.f/D_)+1e-5f);
      hn_s[e0] = h0*isq*g1_s[e0] + b1_s[e0];
      hn_s[e1] = h1*isq*g1_s[e1] + b1_s[e1];
    }
    t0 = xB.x + bp_s[e0]; t1 = xB.y + bp_s[e1];
    mean = wred(t0+t1)*(1.f/D_);
    h0 = t0-mean; h1 = t1-mean;
    xg_s[r1][e0] = h0*g1_s[e0];
    xg_s[r1][e1] = h1*g1_s[e1];
    vv = h0*h0 + h1*h1;
    d0 = h0*w_s[0][e0] + h1*w_s[0][e1];
    d1 = h0*w_s[1][e0] + h1*w_s[1][e1];
    d2 = h0*w_s[2][e0] + h1*w_s[2][e1];
    #pragma unroll
    for (int off=32; off; off>>=1){
      vv += __shfl_xor(vv,off); d0 += __shfl_xor(d0,off);
      d1 += __shfl_xor(d1,off); d2 += __shfl_xor(d2,off);
    }
    if (lane==0){ varx_s[r1]=vv*(1.f/D_);
      dxp_s[r1][0]=d0; dxp_s[r1][1]=d1; dxp_s[r1][2]=d2; }
    if (r1 == i){
      float isq = rsqrtf(vv*(1.f/D_)+1e-5f);
      hn_s[e0] = h0*isq*g1_s[e0] + b1_s[e0];
      hn_s[e1] = h1*isq*g1_s[e1] + b1_s[e1];
    }
  }
  float dc0=0.f, dc1=0.f, dc2=0.f;
  if (tid < L_){
    int c = tid >> 5;
    dc0 = ck0 - cq_s[c][0]; dc1 = ck1 - cq_s[c][1]; dc2 = ck2 - cq_s[c][2];
    dc_s[0][tid]=dc0; dc_s[1][tid]=dc1; dc_s[2][tid]=dc2;
  }
  if (wave >= 8 && wave < 11){
    int j = wave - 8;
    float s = w_s[j][lane] + w_s[j][lane+64];
    s = wred(s);
    if (lane==0) mwp_s[j] = s*(1.f/D_);
  }
  if (wave >= 10){
    int idx = wave - 10;
    int ja = (idx>=3) + (idx>=5);
    int jb = idx - (idx>=3)*2 - (idx>=5);
    float s = w_s[ja][lane]*w_s[jb][lane] + w_s[ja][lane+64]*w_s[jb][lane+64];
    s = wred(s);
    if (lane==0) P6_s[idx] = s;
  }
  __syncthreads();   // B2

  // ===== P2: is_s (tid<864, reg dc) + wcg =====
  if (tid < L_){
    int n = tid & 31;
    float m0 = mwp_s[0], m1 = mwp_s[1], m2 = mwp_s[2];
    float M00 = P6_s[0]-D_*m0*m0, M01 = P6_s[1]-D_*m0*m1;
    float M02 = P6_s[2]-D_*m0*m2, M11 = P6_s[3]-D_*m1*m1;
    float M12 = P6_s[4]-D_*m1*m2, M22 = P6_s[5]-D_*m2*m2;
    float quad = dc0*dc0*M00 + dc1*dc1*M11 + dc2*dc2*M22
               + 2.f*(dc0*dc1*M01 + dc0*dc2*M02 + dc1*dc2*M12);
    float lin  = dc0*dxp_s[n][0] + dc1*dxp_s[n][1] + dc2*dxp_s[n][2];
    float E = varx_s[n] + (quad + 2.f*lin)*(1.f/D_);
    is_s[tid] = rsqrtf(fmaxf(E, 0.f) + 1e-5f);
  }
  if (tid < 384){ int j=tid>>7, e=tid&127;
    wcg_s[j][e] = (w_s[j][e] - mwp_s[j])*g1_s[e]; }
  __syncthreads();   // B3

  // ===== P3: q partials (wq4, 32 es x 32 d4) =====
  {
    float4 acc = {0.f,0.f,0.f,0.f};
    #pragma unroll
    for (int k=0;k<4;k++){
      float h = hn_s[es*4+k];
      acc.x += h*wq4[k].x; acc.y += h*wq4[k].y;
      acc.z += h*wq4[k].z; acc.w += h*wq4[k].w;
    }
    pf4[es*32 + d4] = acc;
  }
  __syncthreads();   // B4

  // ===== P4 (FUSED): q-combine in-wave + u via shfl broadcast =====
  {
    int h = wave >> 1, sub = wave & 1;
    float qv = 0.f;
    if (lane < 16){
      qv = bq_s[h*16 + lane];
      #pragma unroll
      for (int s=0;s<32;s++) qv += pf_s[s*D_ + h*16 + lane];
    }
    int e = sub*64 + lane;
    float u = 0.f;
    #pragma unroll
    for (int kq=0; kq<4; kq++){
      u += wk4[kq].x*__shfl(qv, kq*4+0) + wk4[kq].y*__shfl(qv, kq*4+1)
         + wk4[kq].z*__shfl(qv, kq*4+2) + wk4[kq].w*__shfl(qv, kq*4+3);
    }
    zz_s[h][e] = u;                    // raw u
    if (sub == 0 && lane < 16) q_s[h*16+lane] = qv;
  }
  __syncthreads();   // B5

  // ===== P5: qAxk partials (4 e-quarters x 256 (h,n)) =====
  {
    int quarter = tid>>8, id = tid&255, h = id>>5, n = id&31;
    float s = 0.f;
    #pragma unroll 8
    for (int e = quarter*32; e < quarter*32+32; e++) s += xg_s[n][e]*zz_s[h][e];
    pf_s[quarter*256 + id] = s;
  }
  __syncthreads();   // B6

  // ===== P6: qAxk combine + S3/qGk =====
  if (tid < 256){
    qAxk_s[tid>>5][tid&31] = pf_s[tid] + pf_s[256+tid]
                           + pf_s[512+tid] + pf_s[768+tid];
  }
  if (wave >= 8){
    int h = wave - 8;
    float u0 = zz_s[h][lane], u1 = zz_s[h][lane+64];
    float s3 = b1_s[lane]*u0 + b1_s[lane+64]*u1;
    if (lane < 16) s3 += q_s[h*16+lane]*bk_s[h*16+lane];
    float qg0 = wcg_s[0][lane]*u0 + wcg_s[0][lane+64]*u1;
    float qg1 = wcg_s[1][lane]*u0 + wcg_s[1][lane+64]*u1;
    float qg2 = wcg_s[2][lane]*u0 + wcg_s[2][lane+64]*u1;
    #pragma unroll
    for (int off=32; off; off>>=1){
      s3  += __shfl_xor(s3,off);  qg0 += __shfl_xor(qg0,off);
      qg1 += __shfl_xor(qg1,off); qg2 += __shfl_xor(qg2,off);
    }
    if (lane==0){ S3_s[h]=s3; qGk_s[h][0]=qg0; qGk_s[h][1]=qg1; qGk_s[h][2]=qg2; }
  }
  __syncthreads();   // B7

  // ===== P7: merged softmax (scores in regs, own-wave max, exp, sums) ===
  int h2 = wave>>1, sub = wave&1, n2 = lane&31, half2 = lane>>5;
  int q4c = sub*2 + half2, c0 = q4c*7, c1 = (q4c==3) ? NC_ : c0+7;
  {
    float qa = qAxk_s[h2][n2];
    float qg0 = qGk_s[h2][0], qg1 = qGk_s[h2][1], qg2 = qGk_s[h2][2];
    float s3 = S3_s[h2];
    bool mk = mask_s[n2] != 0;
    float sc[7];
    float M = -3.0e38f;
    #pragma unroll
    for (int t=0; t<7; t++){
      int c = c0+t;
      if (c < c1){
        int l = c*N_ + n2;
        float v = 0.25f*(is_s[l]*(qa + dc_s[0][l]*qg0 + dc_s[1][l]*qg1
                                     + dc_s[2][l]*qg2) + s3);
        sc[t] = mk ? v : -1e9f;
      } else sc[t] = -3.0e38f;
      M = fmaxf(M, sc[t]);
    }
    #pragma unroll
    for (int off=32; off; off>>=1) M = fmaxf(M, __shfl_xor(M, off));
    if (lane==0) pmax_s[h2][sub] = M;
    float S=0.f, Tn=0.f, rr0=0.f, rr1=0.f, rr2=0.f;
    #pragma unroll
    for (int t=0; t<7; t++){
      int c = c0+t;
      if (c < c1){
        int l = c*N_ + n2;
        float w_ = __expf(sc[t] - M);
        float tt = w_ * is_s[l];
        S += w_; Tn += tt;
        rr0 += tt*dc_s[0][l]; rr1 += tt*dc_s[1][l]; rr2 += tt*dc_s[2][l];
      }
    }
    float Tn2 = Tn + __shfl_xor(Tn, 32);
    if (lane < 32) Tnp_s[h2][sub][lane] = Tn2;
    #pragma unroll
    for (int off=32; off; off>>=1){
      S   += __shfl_xor(S,off);   rr0 += __shfl_xor(rr0,off);
      rr1 += __shfl_xor(rr1,off); rr2 += __shfl_xor(rr2,off);
    }
    if (lane==0){ Sp_s[h2][sub]=S;
      RDp_s[h2][sub][0]=rr0; RDp_s[h2][sub][1]=rr1; RDp_s[h2][sub][2]=rr2; }
  }
  __syncthreads();   // B8

  // ===== P8: ZZ_h[e] with sub-wave rescale combine =====
  {
    int h = tid>>7, e = tid&127;
    float M0 = pmax_s[h][0], M1 = pmax_s[h][1];
    float Mx = fmaxf(M0, M1);
    float f0 = __expf(M0-Mx), f1 = __expf(M1-Mx);
    float S = Sp_s[h][0]*f0 + Sp_s[h][1]*f1;
    float rS = 1.f / fmaxf(S, 1e-30f);
    float z = 0.f;
    #pragma unroll 8
    for (int n=0; n<N_; n++){
      float Tn = Tnp_s[h][0][n]*f0 + Tnp_s[h][1][n]*f1;
      z += Tn * xg_s[n][e];
    }
    float R0 = RDp_s[h][0][0]*f0 + RDp_s[h][1][0]*f1;
    float R1 = RDp_s[h][0][1]*f0 + RDp_s[h][1][1]*f1;
    float R2 = RDp_s[h][0][2]*f0 + RDp_s[h][1][2]*f1;
    z += R0*wcg_s[0][e] + R1*wcg_s[1][e] + R2*wcg_s[2][e];
    zz_s[h][e] = z*rS + b1_s[e];
  }
  __syncthreads();   // B9

  // ===== P9: Wv partials (wv4) -> pf =====
  {
    int h = d4 >> 2;
    float4 acc = {0.f,0.f,0.f,0.f};
    #pragma unroll
    for (int k=0;k<4;k++){
      float zv = zz_s[h][es*4+k];
      acc.x += zv*wv4[k].x; acc.y += zv*wv4[k].y;
      acc.z += zv*wv4[k].z; acc.w += zv*wv4[k].w;
    }
    pf4[es*32 + d4] = acc;
  }
  __syncthreads();   // B10

  // ===== P10 (FUSED): att-combine in-wave + Wo partials -> pf2 =====
  {
    float attv = 0.f;
    if (lane < 8){
      attv = bv_s[8*wave + lane];
      #pragma unroll
      for (int s=0;s<32;s++) attv += pf_s[s*D_ + 8*wave + lane];
    }
    int half = lane >> 5;
    float4 acc = {0.f,0.f,0.f,0.f};
    #pragma unroll
    for (int k=0;k<4;k++){
      float av = __shfl(attv, half*4 + k);
      acc.x += av*wo4[k].x; acc.y += av*wo4[k].y;
      acc.z += av*wo4[k].z; acc.w += av*wo4[k].w;
    }
    pf24[es*32 + d4] = acc;
  }
  __syncthreads();   // B11

  // ===== P11: y + LN2 (wave 0); W1 full prefetch (all waves) =====
  int e8 = tid>>7, c4 = tid&127;       // FFN1 mapping
  float4 w14[16];
  #pragma unroll
  for (int k=0;k<16;k++)
    w14[k] = *(const float4*)(W1 + (size_t)(e8*16+k)*DFF_ + c4*4);
  if (wave == 0){
    float y0 = xI.x + bp_s[e0] + bo_s[e0];
    float y1 = xI.y + bp_s[e1] + bo_s[e1];
    #pragma unroll
    for (int s=0;s<32;s++){
      float2 p = *(const float2*)&pf2_s[s*D_ + e0];
      y0 += p.x; y1 += p.y;
    }
    y_s[e0] = y0; y_s[e1] = y1;
    float mean = wred(y0+y1)*(1.f/D_);
    float v0 = y0-mean, v1 = y1-mean;
    float var = wred(v0*v0+v1*v1)*(1.f/D_);
    float isd = rsqrtf(var + 1e-5f);
    hn2_s[e0] = v0*isd*g2_s[e0] + b2_s[e0];
    hn2_s[e1] = v1*isd*g2_s[e1] + b2_s[e1];
  }
  __syncthreads();   // B12

  // ===== P12: FFN1 partials (w14) -> pf as [8][512] =====
  {
    float4 acc = {0.f,0.f,0.f,0.f};
    #pragma unroll
    for (int k=0;k<16;k++){
      float h = hn2_s[e8*16+k];
      acc.x += h*w14[k].x; acc.y += h*w14[k].y;
      acc.z += h*w14[k].z; acc.w += h*w14[k].w;
    }
    pf4[e8*128 + c4] = acc;
  }
  __syncthreads();   // B13

  // ===== P13: relu combine; W2 full prefetch =====
  int js = tid>>5;                     // FFN2 mapping
  float4 w24[16];
  #pragma unroll
  for (int k=0;k<16;k++)
    w24[k] = *(const float4*)(W2 + (size_t)(js*16+k)*D_ + d4*4);
  if (tid < DFF_){
    float a = bf1_s[tid];
    #pragma unroll
    for (int s=0;s<8;s++) a += pf_s[s*DFF_+tid];
    f_s[tid] = fmaxf(a, 0.f);
  }
  __syncthreads();   // B14

  // ===== P14: FFN2 partials (w24) -> pf2 as [32][128] =====
  {
    float4 acc = {0.f,0.f,0.f,0.f};
    #pragma unroll
    for (int k=0;k<16;k++){
      float fv = f_s[js*16+k];
      acc.x += fv*w24[k].x; acc.y += fv*w24[k].y;
      acc.z += fv*w24[k].z; acc.w += fv*w24[k].w;
    }
    pf24[js*32 + d4] = acc;
  }
  __syncthreads();   // B15

  // ===== P15: out =====
  if (tid < D_){
    float a = y_s[tid] + bfb2_s[tid];
    #pragma unroll
    for (int s=0;s<32;s++) a += pf2_s[s*D_+tid];
    out[(size_t)bi*D_ + tid] = a;
  }
}

extern "C" void kernel_launch(void* const* d_in, const int* in_sizes, int n_in,
                              void* d_out, int out_size, void* d_ws, size_t ws_size,
                              hipStream_t stream){
  const float* x      = (const float*)d_in[0];
  const int*   mask   = (const int*)  d_in[1];
  const float* coords = (const float*)d_in[2];
  const float* Wp     = (const float*)d_in[3];
  const float* bp     = (const float*)d_in[4];
  const float* Wq     = (const float*)d_in[5];
  const float* bq     = (const float*)d_in[6];
  const float* Wk     = (const float*)d_in[7];
  const float* bk     = (const float*)d_in[8];
  const float* Wv     = (const float*)d_in[9];
  const float* bv     = (const float*)d_in[10];
  const float* Wo     = (const float*)d_in[11];
  const float* bo     = (const float*)d_in[12];
  const float* g1     = (const float*)d_in[13];
  const float* b1     = (const float*)d_in[14];
  const float* g2     = (const float*)d_in[15];
  const float* b2     = (const float*)d_in[16];
  const float* W1     = (const float*)d_in[17];
  const float* bf1    = (const float*)d_in[18];
  const float* W2     = (const float*)d_in[19];
  const float* bfb2   = (const float*)d_in[20];

  k_fused<<<B_*N_, 1024, 0, stream>>>(x, mask, coords, Wp, bp, Wq, bq, Wk, bk,
                                      Wv, bv, Wo, bo, g1, b1, g2, b2,
                                      W1, bf1, W2, bfb2, (float*)d_out);
}

// Round 8
// 112.391 us; speedup vs baseline: 1.0698x; 1.0382x over previous
//
#include <hip/hip_runtime.h>

// AtomEncoderLayer fused single-kernel (round-3 configuration — best verified,
// 112.65 us). B=4, N=32, D=128, H=8, NC=27, DK=16, DFF=512, L=864.
// One block per (b,i), 1024 threads (16 waves), 18 barriers.
// Structure: latency-chain optimized —
//  - all weight tiles register-PREFETCHED one phase early (addresses are
//    data-independent; the vmcnt drain at the next barrier is the wait,
//    hidden under the preceding phase's compute)
//  - float4 weight loads: Wq/Wv/Wo as 32 e-slots x 32 d4-groups, W1/W2 as
//    16 float4 per thread
//  - scores held in registers; is_s computation hoisted (local M6 recompute)
// Perturbations that REGRESSED (do not re-apply): W1/W2 chunked prefetch (R4),
// phase merging via owner-wave hn_i / merged softmax (R5), wave-owned scalar
// column gathers (R6), P0 drain consolidation + shfl-fused combines (R7).

#define B_ 4
#define N_ 32
#define D_ 128
#define H_ 8
#define NC_ 27
#define DFF_ 512
#define L_ (NC_*N_)        // 864

__device__ __forceinline__ float wred(float v){
  #pragma unroll
  for (int off = 32; off; off >>= 1) v += __shfl_xor(v, off);
  return v;
}

__global__ __launch_bounds__(1024) void k_fused(
    const float* __restrict__ x, const int* __restrict__ mask,
    const float* __restrict__ coords,
    const float* __restrict__ Wp, const float* __restrict__ bp,
    const float* __restrict__ Wq, const float* __restrict__ bq,
    const float* __restrict__ Wk, const float* __restrict__ bk,
    const float* __restrict__ Wv, const float* __restrict__ bv,
    const float* __restrict__ Wo, const float* __restrict__ bo,
    const float* __restrict__ g1, const float* __restrict__ b1,
    const float* __restrict__ g2, const float* __restrict__ b2,
    const float* __restrict__ W1, const float* __restrict__ bf1,
    const float* __restrict__ W2, const float* __restrict__ bfb2,
    float* __restrict__ out)
{
  __shared__ float is_s[L_];           // inv_std per key
  __shared__ float dc_s[3][L_];        // rel-coords cache
  __shared__ float xg_s[N_][D_+1];     // centered x * g1; +1 pad
  __shared__ float zz_s[H_][D_+1];     // u_h then ZZ_h; +1 pad
  __shared__ float w_s[3][D_];         // raw Wp rows
  __shared__ float wcg_s[3][D_];       // centered Wp * g1
  __shared__ float g1_s[D_], b1_s[D_], bp_s[D_], bq_s[D_], bk_s[D_];
  __shared__ float g2_s[D_], b2_s[D_], bv_s[D_], bo_s[D_], bfb2_s[D_];
  __shared__ float bf1_s[DFF_];
  __shared__ float q_s[D_], hn_s[D_], hn2_s[D_], att_s[D_], y_s[D_];
  __shared__ float qAxk_s[H_][N_];
  __shared__ float qGk_s[H_][3];
  __shared__ float S3_s[H_];
  __shared__ float varx_s[N_];
  __shared__ float dxp_s[N_][3];
  __shared__ int   mask_s[N_];
  __shared__ float cq_s[NC_][3];
  __shared__ float mwp_s[3], P6_s[6];
  __shared__ float pmax_s[H_][2];
  __shared__ float Tnp_s[H_][2][N_];
  __shared__ float Sp_s[H_][2], RDp_s[H_][2][3];
  __shared__ float f_s[DFF_];
  __shared__ float pf_s[4096];         // 16KB partial buffer, multi-shape
  float4* pf4 = (float4*)pf_s;

  int bi = blockIdx.x;                 // b*32+i
  int b = bi >> 5, i = bi & 31;
  int tid = threadIdx.x, wave = tid >> 6, lane = tid & 63;
  int es = tid >> 5, d4 = tid & 31;    // 32 e-slots x 32 d4 mapping

  // ================= phase 0: stage + prefetch Wq/Wk ==================
  int r0 = wave*2, r1 = wave*2+1;
  float xa0 = x[(size_t)(b*N_+r0)*D_ + lane];
  float xa1 = x[(size_t)(b*N_+r0)*D_ + lane+64];
  float xb0 = x[(size_t)(b*N_+r1)*D_ + lane];
  float xb1 = x[(size_t)(b*N_+r1)*D_ + lane+64];
  float xi0 = 0.f, xi1 = 0.f;
  if (wave == 0){ xi0 = x[(size_t)bi*D_+lane]; xi1 = x[(size_t)bi*D_+lane+64]; }
  float ck0=0.f, ck1=0.f, ck2=0.f;
  if (tid < L_){
    int c = tid >> 5, n = tid & 31;
    const float* ck = coords + ((size_t)(b*NC_+c)*N_ + n)*3;
    ck0 = ck[0]; ck1 = ck[1]; ck2 = ck[2];
  }
  // prefetch Wq tile for phase 3 (es,d4): rows es*4..+3, cols d4*4..+3
  float4 wq4[4];
  #pragma unroll
  for (int k=0;k<4;k++)
    wq4[k] = *(const float4*)(Wq + (size_t)(es*4+k)*D_ + d4*4);
  // prefetch Wk tile for phase 5 (h=tid>>7, e=tid&127): cols h*16..+15
  float4 wk4[4];
  {
    int h = tid>>7, e = tid&127;
    #pragma unroll
    for (int k=0;k<4;k++)
      wk4[k] = *(const float4*)(Wk + (size_t)e*D_ + h*16 + k*4);
  }
  if (tid < 384) w_s[tid>>7][tid&127] = Wp[tid];
  if      (tid < 128)  g1_s[tid]      = g1[tid];
  else if (tid < 256)  b1_s[tid-128]  = b1[tid-128];
  else if (tid < 384)  bp_s[tid-256]  = bp[tid-256];
  else if (tid < 512)  bq_s[tid-384]  = bq[tid-384];
  else if (tid < 640)  bk_s[tid-512]  = bk[tid-512];
  else if (tid < 768)  g2_s[tid-640]  = g2[tid-640];
  else if (tid < 896)  b2_s[tid-768]  = b2[tid-768];
  else                 bv_s[tid-896]  = bv[tid-896];
  if      (tid < 128)  bo_s[tid]      = bo[tid];
  else if (tid < 256)  bfb2_s[tid-128]= bfb2[tid-128];
  else if (tid < 768)  bf1_s[tid-256] = bf1[tid-256];
  else if (tid < 800)  mask_s[tid-768]= mask[b*N_ + (tid-768)];
  else if (tid < 881){
    int t = tid-800;
    cq_s[t/3][t%3] = coords[((size_t)(b*NC_ + t/3)*N_ + i)*3 + t%3];
  }
  __syncthreads();   // B1

  // ========= phase 1: rows (xg,varx,dxp), dc, Wp means + P6 ===========
  {
    float t0 = xa0 + bp_s[lane], t1 = xa1 + bp_s[lane+64];
    float mean = wred(t0+t1)*(1.f/D_);
    float h0 = t0-mean, h1 = t1-mean;
    xg_s[r0][lane]    = h0*g1_s[lane];
    xg_s[r0][lane+64] = h1*g1_s[lane+64];
    float vv = h0*h0 + h1*h1;
    float d0 = h0*w_s[0][lane] + h1*w_s[0][lane+64];
    float d1 = h0*w_s[1][lane] + h1*w_s[1][lane+64];
    float d2 = h0*w_s[2][lane] + h1*w_s[2][lane+64];
    #pragma unroll
    for (int off=32; off; off>>=1){
      vv += __shfl_xor(vv,off); d0 += __shfl_xor(d0,off);
      d1 += __shfl_xor(d1,off); d2 += __shfl_xor(d2,off);
    }
    if (lane==0){ varx_s[r0]=vv*(1.f/D_);
      dxp_s[r0][0]=d0; dxp_s[r0][1]=d1; dxp_s[r0][2]=d2; }
    t0 = xb0 + bp_s[lane]; t1 = xb1 + bp_s[lane+64];
    mean = wred(t0+t1)*(1.f/D_);
    h0 = t0-mean; h1 = t1-mean;
    xg_s[r1][lane]    = h0*g1_s[lane];
    xg_s[r1][lane+64] = h1*g1_s[lane+64];
    vv = h0*h0 + h1*h1;
    d0 = h0*w_s[0][lane] + h1*w_s[0][lane+64];
    d1 = h0*w_s[1][lane] + h1*w_s[1][lane+64];
    d2 = h0*w_s[2][lane] + h1*w_s[2][lane+64];
    #pragma unroll
    for (int off=32; off; off>>=1){
      vv += __shfl_xor(vv,off); d0 += __shfl_xor(d0,off);
      d1 += __shfl_xor(d1,off); d2 += __shfl_xor(d2,off);
    }
    if (lane==0){ varx_s[r1]=vv*(1.f/D_);
      dxp_s[r1][0]=d0; dxp_s[r1][1]=d1; dxp_s[r1][2]=d2; }
  }
  float dc0=0.f, dc1=0.f, dc2=0.f;
  if (tid < L_){
    int c = tid >> 5;
    dc0 = ck0 - cq_s[c][0]; dc1 = ck1 - cq_s[c][1]; dc2 = ck2 - cq_s[c][2];
    dc_s[0][tid]=dc0; dc_s[1][tid]=dc1; dc_s[2][tid]=dc2;
  }
  if (wave >= 8 && wave < 11){
    int j = wave - 8;
    float s = w_s[j][lane] + w_s[j][lane+64];
    s = wred(s);
    if (lane==0) mwp_s[j] = s*(1.f/D_);
  }
  if (wave >= 10){
    int idx = wave - 10;
    int ja = (idx>=3) + (idx>=5);
    int jb = idx - (idx>=3)*2 - (idx>=5);
    float s = w_s[ja][lane]*w_s[jb][lane] + w_s[ja][lane+64]*w_s[jb][lane+64];
    s = wred(s);
    if (lane==0) P6_s[idx] = s;
  }
  __syncthreads();   // B2

  // ========= phase 2: is_s (hoisted), wcg, hn_i ===========
  if (tid < L_){
    int n = tid & 31;
    float m0 = mwp_s[0], m1 = mwp_s[1], m2 = mwp_s[2];
    float M00 = P6_s[0]-D_*m0*m0, M01 = P6_s[1]-D_*m0*m1;
    float M02 = P6_s[2]-D_*m0*m2, M11 = P6_s[3]-D_*m1*m1;
    float M12 = P6_s[4]-D_*m1*m2, M22 = P6_s[5]-D_*m2*m2;
    float quad = dc0*dc0*M00 + dc1*dc1*M11 + dc2*dc2*M22
               + 2.f*(dc0*dc1*M01 + dc0*dc2*M02 + dc1*dc2*M12);
    float lin  = dc0*dxp_s[n][0] + dc1*dxp_s[n][1] + dc2*dxp_s[n][2];
    float E = varx_s[n] + (quad + 2.f*lin)*(1.f/D_);
    is_s[tid] = rsqrtf(fmaxf(E, 0.f) + 1e-5f);
  }
  if (tid < 384){ int j=tid>>7, e=tid&127;
    wcg_s[j][e] = (w_s[j][e] - mwp_s[j])*g1_s[e]; }
  if (tid >= 896){ int e = tid-896;
    hn_s[e] = xg_s[i][e]*rsqrtf(varx_s[i]+1e-5f) + b1_s[e]; }
  __syncthreads();   // B3

  // ========= phase 3: q partials, prefetched Wq (32 es x 32 d4) =========
  {
    float4 acc = {0.f,0.f,0.f,0.f};
    #pragma unroll
    for (int k=0;k<4;k++){
      float h = hn_s[es*4+k];
      acc.x += h*wq4[k].x; acc.y += h*wq4[k].y;
      acc.z += h*wq4[k].z; acc.w += h*wq4[k].w;
    }
    pf4[es*32 + d4] = acc;
  }
  __syncthreads();   // B4

  // ========= phase 4: q combine =========
  if (tid < D_){
    float a = bq_s[tid];
    #pragma unroll
    for (int s=0;s<32;s++) a += pf_s[s*D_+tid];
    q_s[tid] = a;
  }
  __syncthreads();   // B5

  // ========= phase 5: u_h[e], prefetched Wk (8h x 128e) =========
  {
    int h = tid>>7, e = tid&127;
    float s = 0.f;
    #pragma unroll
    for (int kq=0; kq<4; kq++){
      s += wk4[kq].x*q_s[h*16+kq*4+0] + wk4[kq].y*q_s[h*16+kq*4+1]
         + wk4[kq].z*q_s[h*16+kq*4+2] + wk4[kq].w*q_s[h*16+kq*4+3];
    }
    zz_s[h][e] = s;                    // raw u
  }
  __syncthreads();   // B6

  // ========= phase 6: qAxk partials (4 e-quarters x 256 (h,n)) =========
  {
    int quarter = tid>>8, id = tid&255, h = id>>5, n = id&31;
    float s = 0.f;
    #pragma unroll 8
    for (int e = quarter*32; e < quarter*32+32; e++) s += xg_s[n][e]*zz_s[h][e];
    pf_s[quarter*256 + id] = s;
  }
  __syncthreads();   // B7

  // ========= phase 7: qAxk combine + S3/qGk =========
  if (tid < 256){
    qAxk_s[tid>>5][tid&31] = pf_s[tid] + pf_s[256+tid]
                           + pf_s[512+tid] + pf_s[768+tid];
  }
  if (wave >= 8){
    int h = wave - 8;
    float u0 = zz_s[h][lane], u1 = zz_s[h][lane+64];
    float s3 = b1_s[lane]*u0 + b1_s[lane+64]*u1;
    if (lane < 16) s3 += q_s[h*16+lane]*bk_s[h*16+lane];
    float qg0 = wcg_s[0][lane]*u0 + wcg_s[0][lane+64]*u1;
    float qg1 = wcg_s[1][lane]*u0 + wcg_s[1][lane+64]*u1;
    float qg2 = wcg_s[2][lane]*u0 + wcg_s[2][lane+64]*u1;
    #pragma unroll
    for (int off=32; off; off>>=1){
      s3  += __shfl_xor(s3,off);  qg0 += __shfl_xor(qg0,off);
      qg1 += __shfl_xor(qg1,off); qg2 += __shfl_xor(qg2,off);
    }
    if (lane==0){ S3_s[h]=s3; qGk_s[h][0]=qg0; qGk_s[h][1]=qg1; qGk_s[h][2]=qg2; }
  }
  __syncthreads();   // B8

  // ========= phase 9: scores in REGISTERS + per-wave max =========
  int h2 = wave>>1, sub = wave&1, n2 = lane&31, half2 = lane>>5;
  int q4 = sub*2 + half2, c0 = q4*7, c1 = (q4==3) ? NC_ : c0+7;
  float sc[7];
  {
    float qa = qAxk_s[h2][n2];
    float qg0 = qGk_s[h2][0], qg1 = qGk_s[h2][1], qg2 = qGk_s[h2][2];
    float s3 = S3_s[h2];
    bool mk = mask_s[n2] != 0;
    float M = -3.0e38f;
    #pragma unroll
    for (int t=0; t<7; t++){
      int c = c0+t;
      if (c < c1){
        int l = c*N_ + n2;
        float v = 0.25f*(is_s[l]*(qa + dc_s[0][l]*qg0 + dc_s[1][l]*qg1
                                     + dc_s[2][l]*qg2) + s3);
        sc[t] = mk ? v : -1e9f;
      } else sc[t] = -3.0e38f;
      M = fmaxf(M, sc[t]);
    }
    #pragma unroll
    for (int off=32; off; off>>=1) M = fmaxf(M, __shfl_xor(M, off));
    if (lane==0) pmax_s[h2][sub] = M;
  }
  __syncthreads();   // B10

  // ========= phase 10: exp + partial sums; prefetch Wv =========
  float4 wv4[4];
  #pragma unroll
  for (int k=0;k<4;k++)
    wv4[k] = *(const float4*)(Wv + (size_t)(es*4+k)*D_ + d4*4);
  {
    float M = fmaxf(pmax_s[h2][0], pmax_s[h2][1]);
    float S=0.f, Tn=0.f, rr0=0.f, rr1=0.f, rr2=0.f;
    #pragma unroll
    for (int t=0; t<7; t++){
      int c = c0+t;
      if (c < c1){
        int l = c*N_ + n2;
        float w_ = __expf(sc[t] - M);
        float tt = w_ * is_s[l];
        S += w_; Tn += tt;
        rr0 += tt*dc_s[0][l]; rr1 += tt*dc_s[1][l]; rr2 += tt*dc_s[2][l];
      }
    }
    float Tn2 = Tn + __shfl_xor(Tn, 32);
    if (lane < 32) Tnp_s[h2][sub][lane] = Tn2;
    #pragma unroll
    for (int off=32; off; off>>=1){
      S   += __shfl_xor(S,off);   rr0 += __shfl_xor(rr0,off);
      rr1 += __shfl_xor(rr1,off); rr2 += __shfl_xor(rr2,off);
    }
    if (lane==0){ Sp_s[h2][sub]=S;
      RDp_s[h2][sub][0]=rr0; RDp_s[h2][sub][1]=rr1; RDp_s[h2][sub][2]=rr2; }
  }
  __syncthreads();   // B11

  // ========= phase 11: ZZ_h[e]; prefetch Wo =========
  float4 wo4[4];
  #pragma unroll
  for (int k=0;k<4;k++)
    wo4[k] = *(const float4*)(Wo + (size_t)(es*4+k)*D_ + d4*4);
  {
    int h = tid>>7, e = tid&127;
    float rS = 1.f / fmaxf(Sp_s[h][0]+Sp_s[h][1], 1e-30f);
    float z = 0.f;
    #pragma unroll 8
    for (int n=0; n<N_; n++){
      float Tn = Tnp_s[h][0][n] + Tnp_s[h][1][n];
      z += Tn * xg_s[n][e];
    }
    float R0 = RDp_s[h][0][0]+RDp_s[h][1][0];
    float R1 = RDp_s[h][0][1]+RDp_s[h][1][1];
    float R2 = RDp_s[h][0][2]+RDp_s[h][1][2];
    z += R0*wcg_s[0][e] + R1*wcg_s[1][e] + R2*wcg_s[2][e];
    zz_s[h][e] = z*rS + b1_s[e];
  }
  __syncthreads();   // B12

  // ========= phase 12: Wv partials (prefetched) =========
  {
    int h = d4 >> 2;                   // uniform over the 4 output d's
    float4 acc = {0.f,0.f,0.f,0.f};
    #pragma unroll
    for (int k=0;k<4;k++){
      float zv = zz_s[h][es*4+k];
      acc.x += zv*wv4[k].x; acc.y += zv*wv4[k].y;
      acc.z += zv*wv4[k].z; acc.w += zv*wv4[k].w;
    }
    pf4[es*32 + d4] = acc;
  }
  __syncthreads();   // B13

  // ========= phase 13: att combine =========
  if (tid < D_){
    float a = bv_s[tid];
    #pragma unroll
    for (int s=0;s<32;s++) a += pf_s[s*D_+tid];
    att_s[tid] = a;
  }
  __syncthreads();   // B14

  // ========= phase 14: Wo partials (prefetched) =========
  {
    float4 acc = {0.f,0.f,0.f,0.f};
    #pragma unroll
    for (int k=0;k<4;k++){
      float av = att_s[es*4+k];
      acc.x += av*wo4[k].x; acc.y += av*wo4[k].y;
      acc.z += av*wo4[k].z; acc.w += av*wo4[k].w;
    }
    pf4[es*32 + d4] = acc;
  }
  __syncthreads();   // B15

  // ========= phase 15: prefetch W1 (all waves); y + LN2 (wave 0) =========
  float4 w14[16];
  {
    int e8 = tid>>7, c4 = tid&127;     // 8 e-slots x 128 col4-groups
    #pragma unroll
    for (int k=0;k<16;k++)
      w14[k] = *(const float4*)(W1 + (size_t)(e8*16+k)*DFF_ + c4*4);
  }
  if (wave == 0){
    float y0 = xi0 + bp_s[lane]    + bo_s[lane];
    float y1 = xi1 + bp_s[lane+64] + bo_s[lane+64];
    #pragma unroll
    for (int s=0;s<32;s++){ y0 += pf_s[s*D_+lane]; y1 += pf_s[s*D_+lane+64]; }
    y_s[lane] = y0; y_s[lane+64] = y1;
    float mean = wred(y0+y1)*(1.f/D_);
    float v0 = y0-mean, v1 = y1-mean;
    float var = wred(v0*v0+v1*v1)*(1.f/D_);
    float isd = rsqrtf(var + 1e-5f);
    hn2_s[lane]    = v0*isd*g2_s[lane]    + b2_s[lane];
    hn2_s[lane+64] = v1*isd*g2_s[lane+64] + b2_s[lane+64];
  }
  __syncthreads();   // B16

  // ========= phase 16: FFN1 partials (prefetched W1) =========
  {
    int e8 = tid>>7, c4 = tid&127;
    float4 acc = {0.f,0.f,0.f,0.f};
    #pragma unroll
    for (int k=0;k<16;k++){
      float h = hn2_s[e8*16+k];
      acc.x += h*w14[k].x; acc.y += h*w14[k].y;
      acc.z += h*w14[k].z; acc.w += h*w14[k].w;
    }
    pf4[e8*128 + c4] = acc;            // pf as [8][512]
  }
  __syncthreads();   // B17

  // ========= phase 17: relu combine; prefetch W2 =========
  float4 w24[16];
  {
    int js = tid>>5;                   // 32 j-slots x 32 d4
    #pragma unroll
    for (int k=0;k<16;k++)
      w24[k] = *(const float4*)(W2 + (size_t)(js*16+k)*D_ + d4*4);
  }
  if (tid < DFF_){
    float a = bf1_s[tid];
    #pragma unroll
    for (int s=0;s<8;s++) a += pf_s[s*DFF_+tid];
    f_s[tid] = fmaxf(a, 0.f);
  }
  __syncthreads();   // B18

  // ========= phase 18: FFN2 partials (prefetched W2) =========
  {
    int js = tid>>5;
    float4 acc = {0.f,0.f,0.f,0.f};
    #pragma unroll
    for (int k=0;k<16;k++){
      float fv = f_s[js*16+k];
      acc.x += fv*w24[k].x; acc.y += fv*w24[k].y;
      acc.z += fv*w24[k].z; acc.w += fv*w24[k].w;
    }
    pf4[js*32 + d4] = acc;             // pf as [32][128]
  }
  __syncthreads();   // B19

  // ========= phase 19: out =========
  if (tid < D_){
    float a = y_s[tid] + bfb2_s[tid];
    #pragma unroll
    for (int s=0;s<32;s++) a += pf_s[s*D_+tid];
    out[(size_t)bi*D_ + tid] = a;
  }
}

extern "C" void kernel_launch(void* const* d_in, const int* in_sizes, int n_in,
                              void* d_out, int out_size, void* d_ws, size_t ws_size,
                              hipStream_t stream){
  const float* x      = (const float*)d_in[0];
  const int*   mask   = (const int*)  d_in[1];
  const float* coords = (const float*)d_in[2];
  const float* Wp     = (const float*)d_in[3];
  const float* bp     = (const float*)d_in[4];
  const float* Wq     = (const float*)d_in[5];
  const float* bq     = (const float*)d_in[6];
  const float* Wk     = (const float*)d_in[7];
  const float* bk     = (const float*)d_in[8];
  const float* Wv     = (const float*)d_in[9];
  const float* bv     = (const float*)d_in[10];
  const float* Wo     = (const float*)d_in[11];
  const float* bo     = (const float*)d_in[12];
  const float* g1     = (const float*)d_in[13];
  const float* b1     = (const float*)d_in[14];
  const float* g2     = (const float*)d_in[15];
  const float* b2     = (const float*)d_in[16];
  const float* W1     = (const float*)d_in[17];
  const float* bf1    = (const float*)d_in[18];
  const float* W2     = (const float*)d_in[19];
  const float* bfb2   = (const float*)d_in[20];

  k_fused<<<B_*N_, 1024, 0, stream>>>(x, mask, coords, Wp, bp, Wq, bq, Wk, bk,
                                      Wv, bv, Wo, bo, g1, b1, g2, b2,
                                      W1, bf1, W2, bfb2, (float*)d_out);
}